// Round 1
// baseline (628.167 us; speedup 1.0000x reference)
//
#include <hip/hip_runtime.h>

// FSQ-style quantizer:
//   z:           [B, 6]  float32
//   percentiles: [8, 6]  float32 (sorted ascending per column)
//   codebook:    [262144, 64] float32
// Outputs (concatenated flat in d_out, all read back as float32):
//   quantized: [B, 64] float32 = codebook[big_index]
//   big_index: [B]     written as float (exact: max 262143 < 2^24)
//
// index_d = max{ j : z_d >= p[j][d] } else 0  ==  clamp(count(z_d >= p[:,d]) - 1, 0, 7)
// big_index = sum_d index_d * basis_d, basis = [1,8,64,512,4096,32768]

#define NDIM 6
#define NLEV 8
#define CH 64
#define ROWS_PER_BLOCK 64
#define THREADS 256

__global__ __launch_bounds__(THREADS) void fsq_kernel(
    const float* __restrict__ z,
    const float* __restrict__ perc,
    const float* __restrict__ codebook,
    float* __restrict__ out_q,
    float* __restrict__ out_idx,
    int B)
{
    __shared__ float s_z[ROWS_PER_BLOCK * NDIM];   // 384 floats
    __shared__ float s_p[NLEV * NDIM];             // 48 floats
    __shared__ int   s_idx[ROWS_PER_BLOCK];

    const int tid = threadIdx.x;
    const long long row0 = (long long)blockIdx.x * ROWS_PER_BLOCK;

    // stage percentiles (48 floats)
    if (tid < NLEV * NDIM) s_p[tid] = perc[tid];

    // stage z tile (coalesced)
    int nrows = ROWS_PER_BLOCK;
    if (row0 + ROWS_PER_BLOCK > (long long)B) nrows = (int)((long long)B - row0);
    const int nz = nrows * NDIM;
    const float* zbase = z + row0 * NDIM;
    for (int i = tid; i < nz; i += THREADS) s_z[i] = zbase[i];
    __syncthreads();

    // phase 1: one thread per row computes big_index
    if (tid < nrows) {
        const int basis[NDIM] = {1, 8, 64, 512, 4096, 32768};
        int big = 0;
        #pragma unroll
        for (int d = 0; d < NDIM; ++d) {
            const float zv = s_z[tid * NDIM + d];
            int cnt = 0;
            #pragma unroll
            for (int j = 0; j < NLEV; ++j)
                cnt += (zv >= s_p[j * NDIM + d]) ? 1 : 0;
            const int idx = (cnt > 0) ? (cnt - 1) : 0;
            big += idx * basis[d];
        }
        s_idx[tid] = big;
        out_idx[row0 + tid] = (float)big;
    }
    __syncthreads();

    // phase 2: cooperative gather-copy, 16 threads x float4 per row
    const int lane = tid & 15;   // 0..15 -> which float4 of the 64-float row
    const int rsub = tid >> 4;   // 0..15 -> row within group of 16
    for (int r = rsub; r < nrows; r += 16) {
        const long long big = (long long)s_idx[r];
        const float4* __restrict__ src =
            (const float4*)(codebook + big * CH);
        float4* __restrict__ dst =
            (float4*)(out_q + (row0 + r) * (long long)CH);
        dst[lane] = src[lane];
    }
}

extern "C" void kernel_launch(void* const* d_in, const int* in_sizes, int n_in,
                              void* d_out, int out_size, void* d_ws, size_t ws_size,
                              hipStream_t stream) {
    const float* z        = (const float*)d_in[0];
    const float* perc     = (const float*)d_in[1];
    const float* codebook = (const float*)d_in[2];

    const int B = in_sizes[0] / NDIM;   // 2,000,000

    float* out_q   = (float*)d_out;                       // [B, 64]
    float* out_idx = (float*)d_out + (long long)B * CH;   // [B]

    const int grid = (B + ROWS_PER_BLOCK - 1) / ROWS_PER_BLOCK;
    fsq_kernel<<<grid, THREADS, 0, stream>>>(z, perc, codebook, out_q, out_idx, B);
}